// Round 22
// baseline (3005.322 us; speedup 1.0000x reference)
//
#include <hip/hip_runtime.h>
#include <stdint.h>

typedef unsigned short u16;
typedef unsigned int u32;
typedef __attribute__((ext_vector_type(4))) float f32x4;
typedef __attribute__((ext_vector_type(8))) short s16x8;
typedef __attribute__((ext_vector_type(4))) int i32x4;

#define T_ 512
#define B_ 256
#define E_ 256
#define H_ 256
#define G3 768
#define WS_ 2032.0f   // W int8 scale (127 / (1/16) bound)
#define L2E 1.44269504f
#define NREC 64       // rec blocks; gemm blocks follow

__device__ __forceinline__ u16 f2bf(float f) {
  u32 u = __builtin_bit_cast(u32, f);
  u += 0x7fffu + ((u >> 16) & 1u);
  return (u16)(u >> 16);
}
__device__ __forceinline__ float bflo(u32 u) {
  return __builtin_bit_cast(float, u << 16);
}
__device__ __forceinline__ float bfhi(u32 u) {
  return __builtin_bit_cast(float, u & 0xffff0000u);
}

// gi layout (permuted, per (t,b) row of 768 u16):
//   idx = w*96 + l15*6 + g*2 + hf  (w=hidcol/32 within gate, hf=(hidcol>>4)&1)
// PRE-SCALED gi: r,z carry x(-log2 e); n carries x(2 log2 e).

// ---------------- kernel 1: prep (Wih->bf16 scaled, Whh->i8, flags) --------
__global__ void prep_kernel(const float* __restrict__ Wih, const float* __restrict__ Whh,
                            const float* __restrict__ bih, const float* __restrict__ bhh,
                            u16* __restrict__ Wih_bf, signed char* __restrict__ Whh_i8,
                            float* __restrict__ bcomb, u32* __restrict__ done) {
  int i = blockIdx.x * 256 + threadIdx.x;
  const int n = G3 * E_;  // 196608
  if (i < n) {
    int row = i >> 8;  // gate row 0..767
    float sc = (row < 512) ? -L2E : 2.f * L2E;
    Wih_bf[i] = f2bf(Wih[i] * sc);
  } else if (i < 2 * n) {
    float w = Whh[i - n];
    int q = (int)rintf(w * WS_);
    q = q > 127 ? 127 : (q < -127 ? -127 : q);
    Whh_i8[i - n] = (signed char)q;
  }
  if (i < G3) {
    float sc = (i < 512) ? -L2E : 2.f * L2E;
    bcomb[i] = (bih[i] + (i < 2 * H_ ? bhh[i] : 0.f)) * sc;  // n keeps b_hh separate
  }
  if (i < T_) done[i] = 0;   // producer progress flags: MUST reset every launch
}

// ---------------- fused kernel: gi producer + GRU consumer ------------------
// blocks 0..63: persistent GRU recurrence (16 waves, R20 structure).
// blocks 64..1087: gi M-tiles (mt = bid-64, t = mt>>1, ascending -> early t
// first). Producer signals done[t] (2 per t) with agent-release; consumer
// acquire-checks done[t+2] before its gi prefetch (check issued at step TOP,
// verified at step END -> latency hidden).

__device__ __forceinline__ void gru_step(
    int tt, const char* __restrict__ gnext,   // gi base for step tt+2 (clamped)
    const u32* __restrict__ dflag,            // &done[t of gnext]
    const i32x4 (&wq)[3][4], i32x4 (&av)[4],
    const char* __restrict__ hread, char* __restrict__ hwrite,
    u32 (&pc)[3],
    float& hm, int lenr, float bhnS, int hf, int rowlane,
    int l15, int lhi, int col) {

  // early acquire-probe of producer progress (result consumed before prefetch)
  u32 dv = __hip_atomic_load(dflag, __ATOMIC_ACQUIRE, __HIP_MEMORY_SCOPE_AGENT);

  // predicated A-fragment loads: only the 16 live-row lanes touch LDS
  if (rowlane) {
#pragma unroll
    for (int ks = 0; ks < 4; ++ks) {
      int abyte = (l15 * 256 + ks * 64 + lhi * 16) ^ ((l15 & 7) << 4);
      av[ks] = *(const i32x4*)(hread + abyte);
    }
  }

  i32x4 acc[3];
#pragma unroll
  for (int g = 0; g < 3; ++g) acc[g] = (i32x4){0, 0, 0, 0};

#pragma unroll
  for (int ks = 0; ks < 4; ++ks) {
    acc[0] = __builtin_amdgcn_mfma_i32_16x16x64_i8(av[ks], wq[0][ks], acc[0], 0, 0, 0);
    acc[1] = __builtin_amdgcn_mfma_i32_16x16x64_i8(av[ks], wq[1][ks], acc[1], 0, 0, 0);
    acc[2] = __builtin_amdgcn_mfma_i32_16x16x64_i8(av[ks], wq[2][ks], acc[2], 0, 0, 0);
  }

  // gates + h update (1 output/lane)
  const float invsRZ = -L2E / (127.0f * WS_);
  const float invsN = 2.f * L2E / (127.0f * WS_);
  {
    float grS = hf ? bfhi(pc[0]) : bflo(pc[0]);
    float gzS = hf ? bfhi(pc[1]) : bflo(pc[1]);
    float gnS = hf ? bfhi(pc[2]) : bflo(pc[2]);
    float ar = (float)acc[0][0] * invsRZ + grS;
    float az = (float)acc[1][0] * invsRZ + gzS;
    float hnS = (float)acc[2][0] * invsN + bhnS;
    float rg = __builtin_amdgcn_rcpf(1.f + __builtin_amdgcn_exp2f(ar));
    float zg = __builtin_amdgcn_rcpf(1.f + __builtin_amdgcn_exp2f(az));
    float preS = gnS + rg * hnS;
    float th = 1.f - 2.f * __builtin_amdgcn_rcpf(1.f + __builtin_amdgcn_exp2f(preS));
    float hnew = th + zg * (hm - th);
    float hsel = (tt < lenr) ? hnew : hm;   // packed-seq freeze
    hm = hsel;

    int q = (__builtin_bit_cast(int, __builtin_fmaf(hsel, 127.f, 12582912.f))) & 0xff;
    int s1 = __builtin_amdgcn_update_dpp(0, q, 0xB1, 0xF, 0xF, true);   // quad[1,0,3,2]
    int p01 = q | (s1 << 8);
    int s2 = __builtin_amdgcn_update_dpp(0, p01, 0x4E, 0xF, 0xF, true); // quad[2,3,0,1]
    u32 packed = (u32)(p01 & 0xffff) | ((u32)s2 << 16);
    if (!(l15 & 3)) {
      int m = 4 * lhi;
      int wbyte = (m * 256 + (col & ~3)) ^ ((m & 7) << 4);
      *(u32*)(hwrite + wbyte) = packed;
    }
  }

  // verify producer reached gnext's timestep, then prefetch (loads float)
  if (dv < 2u) {
    int guard = 0;
    do {
      __builtin_amdgcn_s_sleep(8);
      dv = __hip_atomic_load(dflag, __ATOMIC_ACQUIRE, __HIP_MEMORY_SCOPE_AGENT);
    } while (dv < 2u && ++guard < (1 << 22));
  }
  {
    const u32* p = (const u32*)gnext;
    pc[0] = p[0];
    pc[1] = p[1];
    pc[2] = p[2];
  }

  // raw barrier: drain LDS ops only; global loads stay in flight
  __builtin_amdgcn_sched_barrier(0);
  asm volatile("s_waitcnt lgkmcnt(0)" ::: "memory");
  __builtin_amdgcn_s_barrier();
  __builtin_amdgcn_sched_barrier(0);
}

__global__ __launch_bounds__(1024, 4) void fused_kernel(
    const float* __restrict__ x,
    const u16* __restrict__ Wih_bf,
    const float* __restrict__ bcomb,
    const signed char* __restrict__ Whh_i8,
    const float* __restrict__ bhh,
    const int* __restrict__ lengths,
    u16* __restrict__ gi,
    float* __restrict__ hout,
    u32* __restrict__ done) {
  __shared__ char smem[131072];
  const int bid = blockIdx.x;
  const int tid = threadIdx.x;

  if (bid >= NREC) {
    // ---------------- producer: one 128-row M-tile of gi -------------------
    const int mt = bid - NREC;
    const int m0 = mt * 128;
    const int t = m0 >> 8;
    const int bh = (m0 >> 7) & 1;
    u16* As = (u16*)smem;
    u16* Bs = (u16*)(smem + 65536);

    if (lengths[bh * 128] > t) {            // active tile
      {
        const float* xt = x + (size_t)m0 * E_;
#pragma unroll
        for (int rep = 0; rep < 8; ++rep) {
          int f = rep * 4096 + tid * 4;
          float4 v = *(const float4*)(xt + f);
          int row = f >> 8, k = f & 255;
          uint2 pv;
          pv.x = ((u32)f2bf(v.y) << 16) | f2bf(v.x);
          pv.y = ((u32)f2bf(v.w) << 16) | f2bf(v.z);
          int byte = (row * 512 + k * 2) ^ ((row & 7) << 4);
          *(uint2*)((char*)As + byte) = pv;
        }
      }
      const int lane = tid & 63, wave = tid >> 6;
      const int wm = wave >> 2, wn = wave & 3;
      const int l15 = lane & 15, lhi = lane >> 4;

      for (int nt = 0; nt < 6; ++nt) {
        const int n0 = nt * 128;
        __syncthreads();  // prev MFMA done with Bs (iter0: A-stage ordering)
        {
          const u16* wt = Wih_bf + (size_t)n0 * E_;
#pragma unroll
          for (int rep = 0; rep < 8; ++rep) {
            int u = rep * 4096 + tid * 4;
            uint2 v = *(const uint2*)(wt + u);
            int row = u >> 8, k = u & 255;
            int byte = (row * 512 + k * 2) ^ ((row & 7) << 4);
            *(uint2*)((char*)Bs + byte) = v;
          }
        }
        __syncthreads();

        f32x4 acc[2][2];
#pragma unroll
        for (int i = 0; i < 2; ++i)
#pragma unroll
          for (int j = 0; j < 2; ++j) acc[i][j] = (f32x4){0.f, 0.f, 0.f, 0.f};

#pragma unroll
        for (int ks = 0; ks < 8; ++ks) {
          s16x8 a[2], b[2];
#pragma unroll
          for (int i = 0; i < 2; ++i) {
            int row = wm * 32 + i * 16 + l15;
            int byte = (row * 512 + (ks * 32 + lhi * 8) * 2) ^ ((row & 7) << 4);
            a[i] = *(const s16x8*)((const char*)As + byte);
          }
#pragma unroll
          for (int j = 0; j < 2; ++j) {
            int row = wn * 32 + j * 16 + l15;
            int byte = (row * 512 + (ks * 32 + lhi * 8) * 2) ^ ((row & 7) << 4);
            b[j] = *(const s16x8*)((const char*)Bs + byte);
          }
#pragma unroll
          for (int i = 0; i < 2; ++i)
#pragma unroll
            for (int j = 0; j < 2; ++j)
              acc[i][j] = __builtin_amdgcn_mfma_f32_16x16x32_bf16(a[i], b[j], acc[i][j], 0, 0, 0);
        }

        // epilogue -> permuted gi
        const int g = nt >> 1;
        const int w96 = (nt & 1) * 4 + wn;
        float bc0 = bcomb[n0 + wn * 32 + l15];
        float bc1 = bcomb[n0 + wn * 32 + 16 + l15];
        int idx0 = w96 * 96 + l15 * 6 + g * 2;
#pragma unroll
        for (int i = 0; i < 2; ++i) {
#pragma unroll
          for (int r = 0; r < 4; ++r) {
            float v0 = acc[i][0][r] + bc0;
            float v1 = acc[i][1][r] + bc1;
            u32 packed;
            asm("v_cvt_pk_bf16_f32 %0, %1, %2" : "=v"(packed) : "v"(v0), "v"(v1));
            int grow = m0 + wm * 32 + i * 16 + 4 * lhi + r;
            *(u32*)((char*)gi + ((size_t)grow * G3 + idx0) * 2) = packed;
          }
        }
      }
    }
    // signal: all stores of this block visible (device fence), then bump done[t]
    __threadfence();
    __syncthreads();
    if (tid == 0)
      __hip_atomic_fetch_add(done + t, 1u, __ATOMIC_RELEASE, __HIP_MEMORY_SCOPE_AGENT);
    return;
  }

  // ---------------- consumer: persistent GRU recurrence ---------------------
  const int wg = bid;                  // 64 wgs x 4 batch rows
  const int cb = tid >> 6;             // wave = col-block of 16 (0..15)
  const int lane = tid & 63;
  const int l15 = lane & 15, lhi = lane >> 4;
  const int col = cb * 16 + l15;
  const int hf = cb & 1;               // wave-uniform gi parity
  const int rowlane = ((l15 & 3) == 0);

  char (*hbf)[16 * 256] = (char (*)[16 * 256])smem;  // 2 x 4KB dbuf

  for (int i = tid; i < 2 * 16 * 256 / 4; i += 1024) ((u32*)hbf[0])[i] = 0;

  i32x4 wq[3][4];
#pragma unroll
  for (int g = 0; g < 3; ++g) {
    int row = g * 256 + col;
#pragma unroll
    for (int ks = 0; ks < 4; ++ks)
      wq[g][ks] = *(const i32x4*)(Whh_i8 + (size_t)row * 256 + ks * 64 + lhi * 16);
  }
#pragma unroll
  for (int g = 0; g < 3; ++g)
#pragma unroll
    for (int ks = 0; ks < 4; ++ks)
      asm volatile("" : "+v"(wq[g][ks]));  // pin; 48 regs fits 128-reg budget

  const float bhnS = bhh[512 + col] * (2.f * L2E);
  const int lenr = lengths[wg * 4 + lhi];
  const int tmax = lengths[wg * 4];    // max length in this row-group (sorted desc)

  float hm = 0.f;
  i32x4 av[4];
#pragma unroll
  for (int ks = 0; ks < 4; ++ks) av[ks] = (i32x4){0, 0, 0, 0};

  const char* gbase = (const char*)gi +
      ((size_t)(wg * 4 + lhi) * G3 + (cb >> 1) * 96 + l15 * 6) * 2;
  const size_t TS = (size_t)B_ * G3 * 2;

  // wait for gi[0], gi[1] then preload
  {
    int guard = 0;
    while (__hip_atomic_load(done + 0, __ATOMIC_ACQUIRE, __HIP_MEMORY_SCOPE_AGENT) < 2u &&
           ++guard < (1 << 24)) __builtin_amdgcn_s_sleep(8);
    int t1 = (tmax > 1) ? 1 : 0;
    guard = 0;
    while (__hip_atomic_load(done + t1, __ATOMIC_ACQUIRE, __HIP_MEMORY_SCOPE_AGENT) < 2u &&
           ++guard < (1 << 24)) __builtin_amdgcn_s_sleep(8);
  }
  u32 pcA[3], pcB[3];
  {
    const u32* p0 = (const u32*)gbase;
    pcA[0] = p0[0]; pcA[1] = p0[1]; pcA[2] = p0[2];
    const u32* p1 = (const u32*)(gbase + (tmax > 1 ? TS : 0));
    pcB[0] = p1[0]; pcB[1] = p1[1]; pcB[2] = p1[2];
  }

  __syncthreads();  // covers hbf zero-init

  for (int t = 0; t < tmax; t += 2) {
    int t2 = (t + 2 < tmax) ? t + 2 : tmax - 1;
    const char* g2 = gbase + (size_t)t2 * TS;
    gru_step(t, g2, done + t2, wq, av, hbf[0], hbf[1], pcA, hm, lenr, bhnS, hf,
             rowlane, l15, lhi, col);
    if (t + 1 < tmax) {
      int t3 = (t + 3 < tmax) ? t + 3 : tmax - 1;
      const char* g3 = gbase + (size_t)t3 * TS;
      gru_step(t + 1, g3, done + t3, wq, av, hbf[1], hbf[0], pcB, hm, lenr, bhnS, hf,
               rowlane, l15, lhi, col);
    }
  }

  hout[(size_t)(wg * 4 + lhi) * 256 + col] = hm;
}

// ---------------- kernel 4: gather by unsorted_indices ---------------------
__global__ void gather_kernel(const float* __restrict__ hs, const int* __restrict__ u,
                              float* __restrict__ out) {
  int b = blockIdx.x, c = threadIdx.x;
  out[(size_t)b * 256 + c] = hs[(size_t)u[b] * 256 + c];
}

// ---------------------------------------------------------------------------
extern "C" void kernel_launch(void* const* d_in, const int* in_sizes, int n_in,
                              void* d_out, int out_size, void* d_ws, size_t ws_size,
                              hipStream_t stream) {
  (void)in_sizes; (void)n_in; (void)out_size; (void)ws_size;
  const float* x = (const float*)d_in[0];
  const float* Wih = (const float*)d_in[1];
  const float* Whh = (const float*)d_in[2];
  const float* bih = (const float*)d_in[3];
  const float* bhh = (const float*)d_in[4];
  const int* lengths = (const int*)d_in[5];
  const int* uidx = (const int*)d_in[6];
  float* out = (float*)d_out;

  char* ws = (char*)d_ws;
  u16* gi = (u16*)(ws);                             // 201326592 B
  u16* Wih_bf = (u16*)(ws + 201326592);             // 393216 B
  signed char* Whh_i8 = (signed char*)(ws + 201719808);  // 196608 B
  float* bcomb = (float*)(ws + 201916416);          // 3072 B
  float* hs = (float*)(ws + 201919488);             // 262144 B
  u32* done = (u32*)(ws + 202181632);               // 2048 B

  hipLaunchKernelGGL(prep_kernel, dim3(1536), dim3(256), 0, stream,
                     Wih, Whh, bih, bhh, Wih_bf, Whh_i8, bcomb, done);
  hipLaunchKernelGGL(fused_kernel, dim3(NREC + 1024), dim3(1024), 0, stream,
                     x, Wih_bf, bcomb, Whh_i8, bhh, lengths, gi, hs, done);
  hipLaunchKernelGGL(gather_kernel, dim3(256), dim3(256), 0, stream, hs, uidx, out);
}

// Round 23
// 528.695 us; speedup vs baseline: 5.6844x; 5.6844x over previous
//
#include <hip/hip_runtime.h>
#include <stdint.h>

typedef unsigned short u16;
typedef unsigned int u32;
typedef __attribute__((ext_vector_type(4))) float f32x4;
typedef __attribute__((ext_vector_type(8))) short s16x8;
typedef __attribute__((ext_vector_type(4))) int i32x4;

#define T_ 512
#define B_ 256
#define E_ 256
#define H_ 256
#define G3 768
#define WS_ 2032.0f   // W int8 scale (127 / (1/16) bound)
#define L2E 1.44269504f

__device__ __forceinline__ u16 f2bf(float f) {
  u32 u = __builtin_bit_cast(u32, f);
  u += 0x7fffu + ((u >> 16) & 1u);
  return (u16)(u >> 16);
}
__device__ __forceinline__ float bflo(u32 u) {
  return __builtin_bit_cast(float, u << 16);
}
__device__ __forceinline__ float bfhi(u32 u) {
  return __builtin_bit_cast(float, u & 0xffff0000u);
}

// gi layout (permuted, per (t,b) row of 768 u16):
//   idx = w*96 + l15*6 + g*2 + hf   (w=col/32, l15=col&15, g=gate, hf=(col>>4)&1)
// gru_rec wave cb (0..15) owns cols cb*16+l15: w=cb>>1, hf=cb&1 (wave parity).
// PRE-SCALED gi: r,z gate values carry x(-log2 e); n gate carries x(2 log2 e).

// ---------------- kernel 1: prep (Wih->bf16 scaled, Whh->i8, biases) -------
__global__ void prep_kernel(const float* __restrict__ Wih, const float* __restrict__ Whh,
                            const float* __restrict__ bih, const float* __restrict__ bhh,
                            u16* __restrict__ Wih_bf, signed char* __restrict__ Whh_i8,
                            float* __restrict__ bcomb) {
  int i = blockIdx.x * 256 + threadIdx.x;
  const int n = G3 * E_;  // 196608
  if (i < n) {
    int row = i >> 8;  // gate row 0..767
    float sc = (row < 512) ? -L2E : 2.f * L2E;
    Wih_bf[i] = f2bf(Wih[i] * sc);
  } else if (i < 2 * n) {
    float w = Whh[i - n];
    int q = (int)rintf(w * WS_);
    q = q > 127 ? 127 : (q < -127 ? -127 : q);
    Whh_i8[i - n] = (signed char)q;
  }
  if (i < G3) {
    float sc = (i < 512) ? -L2E : 2.f * L2E;
    bcomb[i] = (bih[i] + (i < 2 * H_ ? bhh[i] : 0.f)) * sc;  // n keeps b_hh separate
  }
}

// ---------------- kernel 2: gi = x @ W_ih^T + bcomb  (bf16 MFMA) -----------
// A-REUSE: 1024 blocks (M-tiles); A staged once, loop over 6 N-tiles.
__global__ __launch_bounds__(256) void gi_gemm(const float* __restrict__ x,
                                               const u16* __restrict__ Wih_bf,
                                               const float* __restrict__ bcomb,
                                               const int* __restrict__ lengths,
                                               u16* __restrict__ gi) {
  const int m0 = blockIdx.x * 128;          // flat row = t*256 + b
  const int t = m0 >> 8;
  const int bh = (m0 >> 7) & 1;
  if (lengths[bh * 128] <= t) return;       // whole tile inactive (lengths sorted desc)

  __shared__ u16 As[128 * 256];             // 64 KB, XOR-swizzled
  __shared__ u16 Bs[128 * 256];             // 64 KB

  const int tid = threadIdx.x;
  {
    const float* xt = x + (size_t)m0 * E_;
#pragma unroll
    for (int rep = 0; rep < 32; ++rep) {
      int f = rep * 1024 + tid * 4;
      float4 v = *(const float4*)(xt + f);
      int row = f >> 8, k = f & 255;
      uint2 pv;
      pv.x = ((u32)f2bf(v.y) << 16) | f2bf(v.x);
      pv.y = ((u32)f2bf(v.w) << 16) | f2bf(v.z);
      int byte = (row * 512 + k * 2) ^ ((row & 7) << 4);
      *(uint2*)((char*)As + byte) = pv;
    }
  }

  const int lane = tid & 63, wave = tid >> 6;
  const int wm = wave >> 1, wn = wave & 1;
  const int l15 = lane & 15, lhi = lane >> 4;

  for (int nt = 0; nt < 6; ++nt) {
    const int n0 = nt * 128;
    __syncthreads();  // prev MFMA done reading Bs (iter0: no-op ordering)
    {
      const u16* wt = Wih_bf + (size_t)n0 * E_;
#pragma unroll
      for (int rep = 0; rep < 32; ++rep) {
        int u = rep * 1024 + tid * 4;
        uint2 v = *(const uint2*)(wt + u);
        int row = u >> 8, k = u & 255;
        int byte = (row * 512 + k * 2) ^ ((row & 7) << 4);
        *(uint2*)((char*)Bs + byte) = v;
      }
    }
    __syncthreads();  // Bs (and As on iter0) staged

    f32x4 acc[4][4];
#pragma unroll
    for (int i = 0; i < 4; ++i)
#pragma unroll
      for (int j = 0; j < 4; ++j) acc[i][j] = (f32x4){0.f, 0.f, 0.f, 0.f};

#pragma unroll
    for (int ks = 0; ks < 8; ++ks) {
      s16x8 a[4], b[4];
#pragma unroll
      for (int i = 0; i < 4; ++i) {
        int row = wm * 64 + i * 16 + l15;
        int byte = (row * 512 + (ks * 32 + lhi * 8) * 2) ^ ((row & 7) << 4);
        a[i] = *(const s16x8*)((const char*)As + byte);
      }
#pragma unroll
      for (int j = 0; j < 4; ++j) {
        int row = wn * 64 + j * 16 + l15;
        int byte = (row * 512 + (ks * 32 + lhi * 8) * 2) ^ ((row & 7) << 4);
        b[j] = *(const s16x8*)((const char*)Bs + byte);
      }
#pragma unroll
      for (int i = 0; i < 4; ++i)
#pragma unroll
        for (int j = 0; j < 4; ++j)
          acc[i][j] = __builtin_amdgcn_mfma_f32_16x16x32_bf16(a[i], b[j], acc[i][j], 0, 0, 0);
    }

    // epilogue: +bias, pack (hf0,hf1) pairs WITHIN thread, store u32 to permuted gi
    const int g = nt >> 1;            // gate index
    const int byodd = nt & 1;
    float bc[4];
#pragma unroll
    for (int j = 0; j < 4; ++j) bc[j] = bcomb[n0 + wn * 64 + j * 16 + l15];

#pragma unroll
    for (int i = 0; i < 4; ++i) {
#pragma unroll
      for (int jp = 0; jp < 2; ++jp) {  // col pair (j=2jp -> hf0, j=2jp+1 -> hf1)
        int idx = (byodd * 4 + wn * 2 + jp) * 96 + l15 * 6 + g * 2;
#pragma unroll
        for (int r = 0; r < 4; ++r) {
          float v0 = acc[i][2 * jp][r] + bc[2 * jp];
          float v1 = acc[i][2 * jp + 1][r] + bc[2 * jp + 1];
          u32 packed;
          asm("v_cvt_pk_bf16_f32 %0, %1, %2" : "=v"(packed) : "v"(v0), "v"(v1));
          int grow = m0 + wm * 64 + i * 16 + 4 * lhi + r;
          *(u32*)((char*)gi + ((size_t)grow * G3 + idx) * 2) = packed;
        }
      }
    }
  }
}

// ---------------- kernel 3: persistent GRU recurrence (int8 W & h) ---------
// 64 wgs x 1024 threads (16 waves, 4/SIMD). wg owns 4 batch rows; wave cb owns
// 16 hidden cols -> 3 gate B-tiles x 16 VGPR = 48 regs PINNED.
// PREDICATED A-LOADS: batch rows live at A-rows 4j -> only lanes l15&3==0
// load h from LDS (16/64 lanes active => 1/4 LDS bank traffic, 2-way max).
// MFMA reads A regs from all lanes regardless of EXEC; dead lanes keep stale
// av values (int8 -> no NaN) feeding C rows nobody reads. av[] persists
// across steps so values are always defined.
// Gates pre-scaled; h: fp32 regs + int8 LDS (8 KB dbuf, XOR-swizzled).
// gi: permuted, 3 dwords/step/thread, prefetched TWO steps ahead.
// Per-step sync: lgkmcnt-only drain + raw s_barrier.

__device__ __forceinline__ void gru_step(
    int tt, const char* __restrict__ gnext,   // gi base for step tt+2 (clamped)
    const i32x4 (&wq)[3][4], i32x4 (&av)[4],
    const char* __restrict__ hread, char* __restrict__ hwrite,
    u32 (&pc)[3],
    float& hm, int lenr, float bhnS, int hf, int rowlane,
    int l15, int lhi, int col) {

  // predicated A-fragment loads: only the 16 live-row lanes touch LDS
  if (rowlane) {
#pragma unroll
    for (int ks = 0; ks < 4; ++ks) {
      int abyte = (l15 * 256 + ks * 64 + lhi * 16) ^ ((l15 & 7) << 4);
      av[ks] = *(const i32x4*)(hread + abyte);
    }
  }

  i32x4 acc[3];
#pragma unroll
  for (int g = 0; g < 3; ++g) acc[g] = (i32x4){0, 0, 0, 0};

  // recurrent GEMM: gh += h @ W_hh^T  (3 tiles pinned in VGPRs)
#pragma unroll
  for (int ks = 0; ks < 4; ++ks) {
    acc[0] = __builtin_amdgcn_mfma_i32_16x16x64_i8(av[ks], wq[0][ks], acc[0], 0, 0, 0);
    acc[1] = __builtin_amdgcn_mfma_i32_16x16x64_i8(av[ks], wq[1][ks], acc[1], 0, 0, 0);
    acc[2] = __builtin_amdgcn_mfma_i32_16x16x64_i8(av[ks], wq[2][ks], acc[2], 0, 0, 0);
  }

  // gates + h update (1 output/lane: batch row lhi, col)
  const float invsRZ = -L2E / (127.0f * WS_);
  const float invsN = 2.f * L2E / (127.0f * WS_);
  {
    float grS = hf ? bfhi(pc[0]) : bflo(pc[0]);
    float gzS = hf ? bfhi(pc[1]) : bflo(pc[1]);
    float gnS = hf ? bfhi(pc[2]) : bflo(pc[2]);
    float ar = (float)acc[0][0] * invsRZ + grS;   // = -log2e * r-preact
    float az = (float)acc[1][0] * invsRZ + gzS;   // = -log2e * z-preact
    float hnS = (float)acc[2][0] * invsN + bhnS;  // = 2log2e * (h-part of n)
    float rg = __builtin_amdgcn_rcpf(1.f + __builtin_amdgcn_exp2f(ar));
    float zg = __builtin_amdgcn_rcpf(1.f + __builtin_amdgcn_exp2f(az));
    float preS = gnS + rg * hnS;                  // = 2log2e * n-preact
    float th = 1.f - 2.f * __builtin_amdgcn_rcpf(1.f + __builtin_amdgcn_exp2f(preS));
    float hnew = th + zg * (hm - th);
    // unconditional select: frozen rows keep (and rewrite) their old state
    float hsel = (tt < lenr) ? hnew : hm;
    hm = hsel;

    // quantize to i8 (magic-number rne) and gather 4 adjacent cols into a dword
    int q = (__builtin_bit_cast(int, __builtin_fmaf(hsel, 127.f, 12582912.f))) & 0xff;
    int s1 = __builtin_amdgcn_update_dpp(0, q, 0xB1, 0xF, 0xF, true);   // quad[1,0,3,2]
    int p01 = q | (s1 << 8);
    int s2 = __builtin_amdgcn_update_dpp(0, p01, 0x4E, 0xF, 0xF, true); // quad[2,3,0,1]
    u32 packed = (u32)(p01 & 0xffff) | ((u32)s2 << 16);
    if (!(l15 & 3)) {
      int m = 4 * lhi;    // A-row for batch row lhi
      int wbyte = (m * 256 + (col & ~3)) ^ ((m & 7) << 4);
      *(u32*)(hwrite + wbyte) = packed;
    }
  }

  // issue gi loads for step tt+2 into this buffer (in flight across 2 barriers)
  {
    const u32* p = (const u32*)gnext;
    pc[0] = p[0];
    pc[1] = p[1];
    pc[2] = p[2];
  }

  // raw barrier: drain LDS ops only; global loads stay in flight
  __builtin_amdgcn_sched_barrier(0);
  asm volatile("s_waitcnt lgkmcnt(0)" ::: "memory");
  __builtin_amdgcn_s_barrier();
  __builtin_amdgcn_sched_barrier(0);
}

__global__ __launch_bounds__(1024, 4) void gru_rec(const u16* __restrict__ gi,
                                                   const signed char* __restrict__ Whh_i8,
                                                   const float* __restrict__ bhh,
                                                   const int* __restrict__ lengths,
                                                   float* __restrict__ hout) {
  const int wg = blockIdx.x;           // 64 wgs x 4 batch rows
  const int tid = threadIdx.x;
  const int cb = tid >> 6;             // wave = col-block of 16 (0..15)
  const int lane = tid & 63;
  const int l15 = lane & 15, lhi = lane >> 4;
  const int col = cb * 16 + l15;
  const int hf = cb & 1;               // wave-uniform gi parity
  const int rowlane = ((l15 & 3) == 0);

  __shared__ char hbf[2][16 * 256];    // 8 KB int8 h (A-rows), dbuf; dead rows stay 0

  for (int i = tid; i < 2 * 16 * 256 / 4; i += 1024) ((u32*)hbf[0])[i] = 0;

  // 3 W tiles (B-operand fragments for this wave's 16 cols) -> pinned (48 regs)
  i32x4 wq[3][4];
#pragma unroll
  for (int g = 0; g < 3; ++g) {
    int row = g * 256 + col;
#pragma unroll
    for (int ks = 0; ks < 4; ++ks)
      wq[g][ks] = *(const i32x4*)(Whh_i8 + (size_t)row * 256 + ks * 64 + lhi * 16);
  }
#pragma unroll
  for (int g = 0; g < 3; ++g)
#pragma unroll
    for (int ks = 0; ks < 4; ++ks)
      asm volatile("" : "+v"(wq[g][ks]));  // pin; 48 regs fits 128-reg/4-wave budget

  const float bhnS = bhh[512 + col] * (2.f * L2E);   // pre-scaled n bias (h-part)
  const int lenr = lengths[wg * 4 + lhi];
  const int tmax = lengths[wg * 4];    // max length in this row-group (sorted desc)

  float hm = 0.f;
  i32x4 av[4];
#pragma unroll
  for (int ks = 0; ks < 4; ++ks) av[ks] = (i32x4){0, 0, 0, 0};

  // permuted gi base: batch row (wg*4 + lhi), slot (w=cb>>1, l15)
  const char* gbase = (const char*)gi +
      ((size_t)(wg * 4 + lhi) * G3 + (cb >> 1) * 96 + l15 * 6) * 2;
  const size_t TS = (size_t)B_ * G3 * 2;  // per-t stride in bytes

  // preload gi for t=0 (pcA) and t=1 (pcB)
  u32 pcA[3], pcB[3];
  {
    const u32* p0 = (const u32*)gbase;
    pcA[0] = p0[0]; pcA[1] = p0[1]; pcA[2] = p0[2];
    const u32* p1 = (const u32*)(gbase + (tmax > 1 ? TS : 0));
    pcB[0] = p1[0]; pcB[1] = p1[1]; pcB[2] = p1[2];
  }

  __syncthreads();  // covers hbf zero-init

  for (int t = 0; t < tmax; t += 2) {
    const char* g2 = gbase + (size_t)(t + 2 < tmax ? t + 2 : tmax - 1) * TS;
    gru_step(t, g2, wq, av, hbf[0], hbf[1], pcA, hm, lenr, bhnS, hf, rowlane, l15, lhi, col);
    if (t + 1 < tmax) {
      const char* g3 = gbase + (size_t)(t + 3 < tmax ? t + 3 : tmax - 1) * TS;
      gru_step(t + 1, g3, wq, av, hbf[1], hbf[0], pcB, hm, lenr, bhnS, hf, rowlane, l15, lhi, col);
    }
  }

  hout[(size_t)(wg * 4 + lhi) * 256 + col] = hm;
}

// ---------------- kernel 4: gather by unsorted_indices ---------------------
__global__ void gather_kernel(const float* __restrict__ hs, const int* __restrict__ u,
                              float* __restrict__ out) {
  int b = blockIdx.x, c = threadIdx.x;
  out[(size_t)b * 256 + c] = hs[(size_t)u[b] * 256 + c];
}

// ---------------------------------------------------------------------------
extern "C" void kernel_launch(void* const* d_in, const int* in_sizes, int n_in,
                              void* d_out, int out_size, void* d_ws, size_t ws_size,
                              hipStream_t stream) {
  (void)in_sizes; (void)n_in; (void)out_size; (void)ws_size;
  const float* x = (const float*)d_in[0];
  const float* Wih = (const float*)d_in[1];
  const float* Whh = (const float*)d_in[2];
  const float* bih = (const float*)d_in[3];
  const float* bhh = (const float*)d_in[4];
  const int* lengths = (const int*)d_in[5];
  const int* uidx = (const int*)d_in[6];
  float* out = (float*)d_out;

  char* ws = (char*)d_ws;
  u16* gi = (u16*)(ws);                             // 201326592 B
  u16* Wih_bf = (u16*)(ws + 201326592);             // 393216 B
  signed char* Whh_i8 = (signed char*)(ws + 201719808);  // 196608 B
  float* bcomb = (float*)(ws + 201916416);          // 3072 B
  float* hs = (float*)(ws + 201919488);             // 262144 B

  hipLaunchKernelGGL(prep_kernel, dim3(1536), dim3(256), 0, stream,
                     Wih, Whh, bih, bhh, Wih_bf, Whh_i8, bcomb);
  hipLaunchKernelGGL(gi_gemm, dim3(1024), dim3(256), 0, stream,
                     x, Wih_bf, bcomb, lengths, gi);
  hipLaunchKernelGGL(gru_rec, dim3(64), dim3(1024), 0, stream,
                     gi, Whh_i8, bhh, lengths, hs);
  hipLaunchKernelGGL(gather_kernel, dim3(256), dim3(256), 0, stream, hs, uidx, out);
}